// Round 1
// baseline (866.651 us; speedup 1.0000x reference)
//
#include <hip/hip_runtime.h>
#include <cstdint>
#include <cstddef>

#define B_ 64
#define N_ 4096
#define D_ 512
#define A_ 128

typedef unsigned short u16;
typedef __attribute__((ext_vector_type(8))) short bf16x8;   // 8 bf16 in 4 VGPRs
typedef __attribute__((ext_vector_type(4))) float f32x4;

__device__ __forceinline__ u16 cvt_bf16(float x) {
    unsigned u = __float_as_uint(x);
    return (u16)((u + 0x7FFFu + ((u >> 16) & 1u)) >> 16);   // RNE
}
__device__ __forceinline__ unsigned pack2_bf16(float a, float b) {
    unsigned ua = __float_as_uint(a), ub = __float_as_uint(b);
    unsigned ra = (ua + 0x7FFFu + ((ua >> 16) & 1u)) >> 16;
    unsigned rb = (ub + 0x7FFFu + ((ub >> 16) & 1u)) >> 16;
    return ra | (rb << 16);
}
__device__ __forceinline__ float fast_tanh(float x) {
    float ax = fabsf(x);
    float e  = __expf(-2.0f * ax);
    float r  = __fdividef(1.0f - e, 1.0f + e);
    return x < 0.0f ? -r : r;
}

// ---------------------------------------------------------------- kernel 0
// W_I [D][A] fp32 -> Wbf [A][K=D] bf16 (transposed, k-contiguous for B-frags)
__global__ void k_conv_w(const float* __restrict__ WI, u16* __restrict__ Wbf) {
    int idx = blockIdx.x * 256 + threadIdx.x;     // 16384 = 128a * 128 d-groups
    int a  = idx & 127;
    int d0 = (idx >> 7) << 2;
    ushort4 r;
    r.x = cvt_bf16(WI[(d0 + 0) * A_ + a]);
    r.y = cvt_bf16(WI[(d0 + 1) * A_ + a]);
    r.z = cvt_bf16(WI[(d0 + 2) * A_ + a]);
    r.w = cvt_bf16(WI[(d0 + 3) * A_ + a]);
    *(ushort4*)&Wbf[a * D_ + d0] = r;
}

// ---------------------------------------------------------------- kernel 1
// q_att[b][a] = tanh(sum_d v_Q[b][d] * W_Q[d][a] + b_Q[a])
__global__ void k_qatt(const float* __restrict__ vQ, const float* __restrict__ WQ,
                       const float* __restrict__ bQ, float* __restrict__ qatt) {
    int b = blockIdx.x, a = threadIdx.x;          // 128 threads
    __shared__ float sq[D_];
    for (int d = a; d < D_; d += 128) sq[d] = vQ[b * D_ + d];
    __syncthreads();
    float acc = bQ[a];
    #pragma unroll 8
    for (int d = 0; d < D_; ++d) acc += sq[d] * WQ[d * A_ + a];
    qatt[b * A_ + a] = fast_tanh(acc);
}

// ---------------------------------------------------------------- kernel 2
// Per block: rows [n0, n0+128) of batch b. Computes logits
// p[b][n] = sum_a tanh(tanh((v_I @ W_I)[n][a]) + q_att[b][a]) * W_p[a]
__global__ void __launch_bounds__(256, 2)
k_gemm(const float* __restrict__ vI, const u16* __restrict__ Wbf,
       const float* __restrict__ qatt, const float* __restrict__ Wp,
       float* __restrict__ p_out) {
    const int b  = blockIdx.y;
    const int n0 = blockIdx.x * 128;
    const int t    = threadIdx.x;
    const int lane = t & 63, wave = t >> 6;
    const int l15  = lane & 15, quad = lane >> 4;

    __shared__ u16 lds_a[128 * 72];   // 128 rows x 64 k, stride 72 (144 B, 16B-aligned)
    __shared__ u16 lds_b[128 * 72];

    f32x4 acc[2][8];
    #pragma unroll
    for (int mt = 0; mt < 2; ++mt)
        #pragma unroll
        for (int nt = 0; nt < 8; ++nt)
            acc[mt][nt] = (f32x4){0.f, 0.f, 0.f, 0.f};

    const float* ga = vI + (size_t)(b * N_ + n0) * D_;
    const int srow = t >> 4;          // 0..15
    const int scol = t & 15;          // 0..15 (units of 4 elements)

    for (int kr = 0; kr < 8; ++kr) {
        const int k0 = kr * 64;
        // stage A: 128 rows x 64 k fp32 -> bf16 LDS
        #pragma unroll
        for (int s = 0; s < 8; ++s) {
            int row = s * 16 + srow;
            float4 v = *(const float4*)(ga + row * D_ + k0 + scol * 4);
            uint2 w;
            w.x = pack2_bf16(v.x, v.y);
            w.y = pack2_bf16(v.z, v.w);
            *(uint2*)&lds_a[row * 72 + scol * 4] = w;
        }
        // stage B: 128 a-rows x 64 k bf16 (L2-hot)
        #pragma unroll
        for (int s = 0; s < 8; ++s) {
            int row = s * 16 + srow;
            ushort4 w = *(const ushort4*)(Wbf + row * D_ + k0 + scol * 4);
            *(ushort4*)&lds_b[row * 72 + scol * 4] = w;
        }
        __syncthreads();
        #pragma unroll
        for (int ks = 0; ks < 2; ++ks) {
            bf16x8 af[2], bfr[8];
            #pragma unroll
            for (int mt = 0; mt < 2; ++mt)
                af[mt] = *(const bf16x8*)&lds_a[(wave * 32 + mt * 16 + l15) * 72 + ks * 32 + quad * 8];
            #pragma unroll
            for (int nt = 0; nt < 8; ++nt)
                bfr[nt] = *(const bf16x8*)&lds_b[(nt * 16 + l15) * 72 + ks * 32 + quad * 8];
            #pragma unroll
            for (int mt = 0; mt < 2; ++mt)
                #pragma unroll
                for (int nt = 0; nt < 8; ++nt)
                    acc[mt][nt] = __builtin_amdgcn_mfma_f32_16x16x32_bf16(
                        af[mt], bfr[nt], acc[mt][nt], 0, 0, 0);
        }
        __syncthreads();
    }

    // epilogue: C/D layout col = lane&15, row = quad*4 + reg
    float qa_v[8], wp_v[8];
    #pragma unroll
    for (int nt = 0; nt < 8; ++nt) {
        int a = nt * 16 + l15;
        qa_v[nt] = qatt[b * A_ + a];
        wp_v[nt] = Wp[a];
    }
    #pragma unroll
    for (int mt = 0; mt < 2; ++mt) {
        #pragma unroll
        for (int r = 0; r < 4; ++r) {
            float s = 0.f;
            #pragma unroll
            for (int nt = 0; nt < 8; ++nt) {
                float t1 = fast_tanh(acc[mt][nt][r]);
                float h  = fast_tanh(t1 + qa_v[nt]);
                s += h * wp_v[nt];
            }
            s += __shfl_xor(s, 1, 16);
            s += __shfl_xor(s, 2, 16);
            s += __shfl_xor(s, 4, 16);
            s += __shfl_xor(s, 8, 16);
            if (l15 == 0)
                p_out[(size_t)b * N_ + n0 + wave * 32 + mt * 16 + quad * 4 + r] = s;
        }
    }
}

// ---------------------------------------------------------------- kernel 3
// in-place softmax over N per b; also u := v_Q
__global__ void k_softmax(float* __restrict__ p, const float* __restrict__ vQ,
                          float* __restrict__ u) {
    int b = blockIdx.x, t = threadIdx.x;          // 256 threads
    int lane = t & 63, wave = t >> 6;
    float* pb = p + (size_t)b * N_;
    float v[16];
    #pragma unroll
    for (int i = 0; i < 4; ++i) {
        float4 x = *(const float4*)(pb + i * 1024 + t * 4);
        v[i * 4 + 0] = x.x; v[i * 4 + 1] = x.y; v[i * 4 + 2] = x.z; v[i * 4 + 3] = x.w;
    }
    float m = -1e30f;
    #pragma unroll
    for (int i = 0; i < 16; ++i) m = fmaxf(m, v[i]);
    #pragma unroll
    for (int o = 32; o > 0; o >>= 1) m = fmaxf(m, __shfl_xor(m, o, 64));
    __shared__ float redm[4], reds[4];
    if (lane == 0) redm[wave] = m;
    __syncthreads();
    m = fmaxf(fmaxf(redm[0], redm[1]), fmaxf(redm[2], redm[3]));
    float sum = 0.f;
    #pragma unroll
    for (int i = 0; i < 16; ++i) { v[i] = __expf(v[i] - m); sum += v[i]; }
    #pragma unroll
    for (int o = 32; o > 0; o >>= 1) sum += __shfl_xor(sum, o, 64);
    if (lane == 0) reds[wave] = sum;
    __syncthreads();
    sum = reds[0] + reds[1] + reds[2] + reds[3];
    float inv = 1.0f / sum;
    #pragma unroll
    for (int i = 0; i < 4; ++i) {
        float4 x = { v[i*4+0] * inv, v[i*4+1] * inv, v[i*4+2] * inv, v[i*4+3] * inv };
        *(float4*)(pb + i * 1024 + t * 4) = x;
    }
    // init u = v_Q (kernel 4 accumulates on top)
    u[b * D_ + t]       = vQ[b * D_ + t];
    u[b * D_ + 256 + t] = vQ[b * D_ + 256 + t];
}

// ---------------------------------------------------------------- kernel 4
// u[b][d] += sum_n p[b][n] * v_I[b][n][d]    (512-row chunks, fp32 atomics)
__global__ void __launch_bounds__(256)
k_wsum(const float* __restrict__ vI, const float* __restrict__ p,
       float* __restrict__ u) {
    const int b  = blockIdx.y;
    const int n0 = blockIdx.x * 512;
    const int t  = threadIdx.x;
    __shared__ float sp[512];
    sp[t]       = p[(size_t)b * N_ + n0 + t];
    sp[t + 256] = p[(size_t)b * N_ + n0 + 256 + t];
    __syncthreads();
    const int rr = t >> 7;            // 0..1: two rows in flight
    const int c  = t & 127;           // float4 column
    const float4* base = (const float4*)(vI + (size_t)(b * N_ + n0 + rr) * D_) + c;
    float a0 = 0.f, a1 = 0.f, a2 = 0.f, a3 = 0.f;
    #pragma unroll 8
    for (int n = 0; n < 512; n += 2) {
        float4 x = base[n * 128];
        float w  = sp[n + rr];
        a0 += w * x.x; a1 += w * x.y; a2 += w * x.z; a3 += w * x.w;
    }
    float* ub = u + b * D_ + c * 4;
    atomicAdd(ub + 0, a0);
    atomicAdd(ub + 1, a1);
    atomicAdd(ub + 2, a2);
    atomicAdd(ub + 3, a3);
}

// ----------------------------------------------------------------
extern "C" void kernel_launch(void* const* d_in, const int* in_sizes, int n_in,
                              void* d_out, int out_size, void* d_ws, size_t ws_size,
                              hipStream_t stream) {
    const float* vI = (const float*)d_in[0];
    const float* vQ = (const float*)d_in[1];
    const float* WI = (const float*)d_in[2];
    const float* WQ = (const float*)d_in[3];
    const float* bQ = (const float*)d_in[4];
    const float* Wp = (const float*)d_in[5];
    // d_in[6] (b_p) is a constant added to all logits -> cancels in softmax.

    float* out_p = (float*)d_out;                    // [B][N]
    float* out_u = out_p + (size_t)B_ * N_;          // [B][D]

    u16*   Wbf  = (u16*)d_ws;                        // [A][D] bf16: 128 KiB
    float* qatt = (float*)((char*)d_ws + (size_t)A_ * D_ * 2); // [B][A]: 32 KiB

    k_conv_w<<<64, 256, 0, stream>>>(WI, Wbf);
    k_qatt<<<B_, 128, 0, stream>>>(vQ, WQ, bQ, qatt);
    k_gemm<<<dim3(N_ / 128, B_), 256, 0, stream>>>(vI, Wbf, qatt, Wp, out_p);
    k_softmax<<<B_, 256, 0, stream>>>(out_p, vQ, out_u);
    k_wsum<<<dim3(N_ / 512, B_), 256, 0, stream>>>(vI, out_p, out_u);
}